// Round 9
// baseline (63.818 us; speedup 1.0000x reference)
//
#include <hip/hip_runtime.h>

typedef __attribute__((ext_vector_type(8))) short bf16x8;
typedef __attribute__((ext_vector_type(4))) float f32x4;

__device__ __forceinline__ unsigned short f2bf(float f) {
  unsigned int u = __float_as_uint(f);
  return (unsigned short)((u + 0x7fffu + ((u >> 16) & 1u)) >> 16);  // RNE
}

__device__ __forceinline__ float bf2f(unsigned short s) {
  return __uint_as_float(((unsigned int)s) << 16);
}

__device__ __forceinline__ unsigned int cvtpk(float a, float b) {
  unsigned int w;  // w = [bf16(a) lo16, bf16(b) hi16], HW RNE
  asm("v_cvt_pk_bf16_f32 %0, %1, %2" : "=v"(w) : "v"(a), "v"(b));
  return w;
}

__device__ __forceinline__ void gload_lds16(const void* g, void* l) {
  __builtin_amdgcn_global_load_lds((const __attribute__((address_space(1))) void*)g,
                                   (__attribute__((address_space(3))) void*)l,
                                   16, 0, 0);
}

// Cast U, V fp32 -> bf16 row-major (12 MB traffic, ~2.5us).
__global__ void castUV(const float4* __restrict__ U, const float4* __restrict__ V,
                       ushort4* __restrict__ Ub, ushort4* __restrict__ Vb) {
  const int NU = 256 * 4096 / 4;
  int i = blockIdx.x * 256 + threadIdx.x;
  const float4* s; ushort4* d; int j;
  if (i < NU) { s = U; d = Ub; j = i; }
  else        { s = V; d = Vb; j = i - NU; }
  float4 v = s[j];
  ushort4 o;
  o.x = f2bf(v.x); o.y = f2bf(v.y); o.z = f2bf(v.z); o.w = f2bf(v.w);
  d[j] = o;
}

// ---------------------------------------------------------------------------
// GEMM1: P[z][m][r] = sum_k x[m, z*256+k] * U[r, z*256+k]   (bf16 partials)
// A = x fp32 (cast fused at frag-read via v_cvt_pk_bf16_f32), B = U bf16.
// BM=64, BN=256, BK=32, waves 1x4 (wave tile 64x64, MREP=NREP=4 -> 16 MFMA
// vs 12 ds_read_b128 per wave-step). z=16 (kChunk=256, nkt=8).
// LDS 48KB -> 3 blocks/CU -> 12 waves/CU. grid 64x1x16 = 1024 blocks.
// Both LDS tiles XOR-swizzled (T2, both-sides: swizzled GLOBAL source col in
// gload_lds staging + same XOR at fragment read) -> 2-way banks (free):
//   A fp32 [64][32]:  slot s (16B): r=s>>3, src col-f32 = 4*((s&7)^(r&7))
//   B bf16 [256][32]: slot s (16B): r=s>>2, src col-bf16 = 8*((s&3)^(r&3))
// ---------------------------------------------------------------------------
__global__ __launch_bounds__(256)
void gemm1_f32a(const float* __restrict__ x, const unsigned short* __restrict__ Ub,
                unsigned short* __restrict__ P) {
  __shared__ __align__(16) float sA[2][64 * 32];            // 2 x 8 KB
  __shared__ __align__(16) unsigned short sB[2][256 * 32];  // 2 x 16 KB

  const int tid = threadIdx.x;
  const int l = tid & 63;
  const int w = tid >> 6;
  const int wn = w * 64;          // waves 1x4: wm = 0
  const int rm = blockIdx.x * 64;
  const int k0base = blockIdx.z * 256;
  const int lr = l & 15;
  const int lg = l >> 4;

  auto stage = [&](int kt, int buf) {
    const int k0 = k0base + kt * 32;
    // B: 4 issues (1024 slots). slot s: row r=s>>2, swizzled col 8*((s&3)^(r&3))
#pragma unroll
    for (int is = 0; is < 4; ++is) {
      int s = is * 256 + tid;
      int r = s >> 2;
      gload_lds16(Ub + (long long)r * 4096 + k0 + 8 * ((s & 3) ^ (r & 3)),
                  (char*)sB[buf] + s * 16);
    }
    // A: 2 issues (512 slots). slot s: row r=s>>3, swizzled col-f32 4*((s&7)^(r&7))
#pragma unroll
    for (int is = 0; is < 2; ++is) {
      int s = is * 256 + tid;
      int r = s >> 3;
      gload_lds16(x + (long long)(rm + r) * 4096 + k0 + 4 * ((s & 7) ^ (r & 7)),
                  (char*)sA[buf] + s * 16);
    }
  };

  f32x4 acc[4][4] = {};

  stage(0, 0);
  for (int kt = 0; kt < 8; ++kt) {
    __syncthreads();  // drains vmcnt: tile kt resident
    if (kt < 7) stage(kt + 1, (kt + 1) & 1);
    const char* a0 = (const char*)sA[kt & 1];
    const char* b0 = (const char*)sB[kt & 1];
    bf16x8 af[4], bfr[4];
#pragma unroll
    for (int m = 0; m < 4; ++m) {
      const int row = m * 16 + lr;
      const int byte0 = row * 128 + ((lg * 32) ^ ((row & 7) << 4));
      float4 f0 = *(const float4*)(a0 + byte0);
      float4 f1 = *(const float4*)(a0 + (byte0 ^ 16));
      // byte0 half holds cols lg*8..+3, byte0^16 holds lg*8+4..+7 (see swizzle)
      unsigned int w0 = cvtpk(f0.x, f0.y), w1 = cvtpk(f0.z, f0.w);
      unsigned int w2 = cvtpk(f1.x, f1.y), w3 = cvtpk(f1.z, f1.w);
      uint4 packed = {w0, w1, w2, w3};
      af[m] = __builtin_bit_cast(bf16x8, packed);
    }
#pragma unroll
    for (int n = 0; n < 4; ++n) {
      const int row = wn + n * 16 + lr;
      bfr[n] = *(const bf16x8*)(b0 + row * 64 + ((lg * 16) ^ ((row & 3) << 4)));
    }
#pragma unroll
    for (int m = 0; m < 4; ++m)
#pragma unroll
      for (int n = 0; n < 4; ++n)
        acc[m][n] = __builtin_amdgcn_mfma_f32_16x16x32_bf16(af[m], bfr[n], acc[m][n], 0, 0, 0);
  }

  // Epilogue: bf16 partials. C/D: col = lane&15, row = (lane>>4)*4 + reg.
  unsigned short* Pz = P + (long long)blockIdx.z * (4096LL * 256);
  const int r0 = rm + lg * 4;
#pragma unroll
  for (int n = 0; n < 4; ++n) {
    const int cc = wn + n * 16 + lr;
#pragma unroll
    for (int m = 0; m < 4; ++m)
#pragma unroll
      for (int i = 0; i < 4; ++i)
        Pz[(long long)(r0 + m * 16 + i) * 256 + cc] = f2bf(acc[m][n][i]);
  }
}

// Sum 16 bf16 split-K partial slices -> bf16 t (fp32 accumulate)
__global__ void reduce16(const ushort4* __restrict__ P, ushort4* __restrict__ t) {
  const int S = 4096 * 256 / 4;
  int i = blockIdx.x * 256 + threadIdx.x;
  float sx = 0, sy = 0, sz = 0, sw = 0;
#pragma unroll
  for (int z = 0; z < 16; ++z) {
    ushort4 v = P[i + z * S];
    sx += bf2f(v.x); sy += bf2f(v.y); sz += bf2f(v.z); sw += bf2f(v.w);
  }
  ushort4 o;
  o.x = f2bf(sx); o.y = f2bf(sy); o.z = f2bf(sz); o.w = f2bf(sw);
  t[i] = o;
}

// ---------------------------------------------------------------------------
// GEMM2: out = t @ V^T + bias, fp32 out. BM=BN=128, BK=32, nkt=8, grid 32x32.
// Same XOR-swizzle on both [128][32] bf16 tiles (8-way -> 2-way banks).
// ---------------------------------------------------------------------------
__global__ __launch_bounds__(256)
void gemm2(const unsigned short* __restrict__ A,
           const unsigned short* __restrict__ B,
           const float* __restrict__ bias,
           float* __restrict__ C) {
  __shared__ __align__(16) unsigned short sA[2][128 * 32];
  __shared__ __align__(16) unsigned short sB[2][128 * 32];

  const int tid = threadIdx.x;
  const int l = tid & 63;
  const int w = tid >> 6;
  const int wm = (w >> 1) * 64;
  const int wn = (w & 1) * 64;
  const int rm = blockIdx.x * 128;
  const int rn = blockIdx.y * 128;
  const int lr = l & 15;
  const int lg = l >> 4;

  auto stage = [&](int kt, int buf) {
    const int k0 = kt * 32;
    // [128][32] bf16 = 512 slots, 2 issues each. slot s: r=s>>2, col 8*((s&3)^(r&3))
#pragma unroll
    for (int is = 0; is < 2; ++is) {
      int s = is * 256 + tid;
      int r = s >> 2;
      gload_lds16(B + (long long)(rn + r) * 256 + k0 + 8 * ((s & 3) ^ (r & 3)),
                  (char*)sB[buf] + s * 16);
    }
#pragma unroll
    for (int is = 0; is < 2; ++is) {
      int s = is * 256 + tid;
      int r = s >> 2;
      gload_lds16(A + (long long)(rm + r) * 256 + k0 + 8 * ((s & 3) ^ (r & 3)),
                  (char*)sA[buf] + s * 16);
    }
  };

  f32x4 acc[4][4] = {};

  stage(0, 0);
  for (int kt = 0; kt < 8; ++kt) {
    __syncthreads();
    if (kt < 7) stage(kt + 1, (kt + 1) & 1);
    const char* a0 = (const char*)sA[kt & 1];
    const char* b0 = (const char*)sB[kt & 1];
    bf16x8 af[4], bfr[4];
#pragma unroll
    for (int m = 0; m < 4; ++m) {
      const int row = wm + m * 16 + lr;
      af[m] = *(const bf16x8*)(a0 + row * 64 + ((lg * 16) ^ ((row & 3) << 4)));
    }
#pragma unroll
    for (int n = 0; n < 4; ++n) {
      const int row = wn + n * 16 + lr;
      bfr[n] = *(const bf16x8*)(b0 + row * 64 + ((lg * 16) ^ ((row & 3) << 4)));
    }
#pragma unroll
    for (int m = 0; m < 4; ++m)
#pragma unroll
      for (int n = 0; n < 4; ++n)
        acc[m][n] = __builtin_amdgcn_mfma_f32_16x16x32_bf16(af[m], bfr[n], acc[m][n], 0, 0, 0);
  }

  const int r0 = rm + wm + lg * 4;
  const int c0 = rn + wn + lr;
#pragma unroll
  for (int n = 0; n < 4; ++n) {
    const int cc = c0 + n * 16;
    const float badd = bias[cc];
#pragma unroll
    for (int m = 0; m < 4; ++m)
#pragma unroll
      for (int i = 0; i < 4; ++i)
        C[(long long)(r0 + m * 16 + i) * 4096 + cc] = acc[m][n][i] + badd;
  }
}

extern "C" void kernel_launch(void* const* d_in, const int* in_sizes, int n_in,
                              void* d_out, int out_size, void* d_ws, size_t ws_size,
                              hipStream_t stream) {
  const float* x    = (const float*)d_in[0];  // [4096,4096]
  const float* U    = (const float*)d_in[1];  // [256,4096]
  const float* V    = (const float*)d_in[2];  // [4096,256]
  const float* bias = (const float*)d_in[3];  // [4096]
  float* out = (float*)d_out;                 // [4096,4096] fp32

  // Workspace (38 MB):
  //  [0,32MB)   P: bf16 split-K partials [16][4096][256]
  //  [32,34MB)  t bf16 [4096][256]
  //  [34,36MB)  U bf16 [256][4096]
  //  [36,38MB)  V bf16 [4096][256]
  char* ws = (char*)d_ws;
  unsigned short* P   = (unsigned short*)ws;
  unsigned short* tb  = (unsigned short*)(ws + (32u << 20));
  unsigned short* Ub  = (unsigned short*)(ws + (34u << 20));
  unsigned short* Vb  = (unsigned short*)(ws + (36u << 20));

  castUV<<<2048, 256, 0, stream>>>((const float4*)U, (const float4*)V,
                                   (ushort4*)Ub, (ushort4*)Vb);

  // GEMM1: grid 64 M-blocks x 16 z = 1024 blocks (3 res/CU by 48KB LDS).
  dim3 g1(64, 1, 16);
  gemm1_f32a<<<g1, 256, 0, stream>>>(x, Ub, P);

  reduce16<<<1024, 256, 0, stream>>>((const ushort4*)P, (ushort4*)tb);

  // GEMM2: grid 32x32.
  dim3 g2(32, 32, 1);
  gemm2<<<g2, 256, 0, stream>>>(tb, Vb, bias, out);
}